// Round 17
// baseline (217.721 us; speedup 1.0000x reference)
//
#include <hip/hip_runtime.h>
#include <hip/hip_fp16.h>
#include <stdint.h>

typedef int v4i __attribute__((ext_vector_type(4)));

#define GLOAD_LDS16(g, l) __builtin_amdgcn_global_load_lds(                  \
    (const __attribute__((address_space(1))) void*)(g),                      \
    (__attribute__((address_space(3))) void*)(l), 16, 0, 0)

// workspace layout (bytes)
#define XQ_OFF 0u
#define XS_OFF 33554432u              // M*K int8
#define W8_OFF 33570816u              // + M*2 fp16 scales

// ---------------------------------------------------------------------------
// Self-classification of input delivery: x widened fp16->f32 has low 13
// mantissa bits zero; w widened int8->int32 has every word in [-128,127].
// ---------------------------------------------------------------------------
__device__ inline bool x_is_f32(const void* xin) {
  const uint32_t* xw = (const uint32_t*)xin;
  bool ok = true;
  #pragma unroll
  for (int i = 0; i < 16; ++i) ok &= ((xw[i] & 0x1FFFu) == 0u);
  return ok;
}
__device__ inline bool w_is_i32(const void* win) {
  const int* wi = (const int*)win;
  bool ok = true;
  #pragma unroll
  for (int i = 0; i < 16; ++i) ok &= (wi[i] >= -128 && wi[i] <= 127);
  return ok;
}

// ---------------------------------------------------------------------------
// Fused prologue: blocks [0, M) quant x rows; blocks [M, M+RW_BLOCKS) repack w.
// ---------------------------------------------------------------------------
#define RW_BLOCKS 1024

__global__ __launch_bounds__(256) void prologue(
    const void* __restrict__ xin, const void* __restrict__ win,
    int8_t* __restrict__ xq, __half* __restrict__ xs,
    int8_t* __restrict__ w8, int K, int M, int wtotal)
{
  const int tid = threadIdx.x;

  if (blockIdx.x >= (unsigned)M) {
    const bool as32 = w_is_i32(win);
    const int bid  = blockIdx.x - M;
    const int gtid = bid * 256 + tid;
    const int nthr = RW_BLOCKS * 256;
    if (as32) {
      const int4* w4 = (const int4*)win;
      uint32_t* dst = (uint32_t*)w8;
      const int n4 = wtotal >> 2;
      for (int i = gtid; i < n4; i += nthr) {
        int4 v = w4[i];
        dst[i] = (uint32_t)(v.x & 255) | ((uint32_t)(v.y & 255) << 8) |
                 ((uint32_t)(v.z & 255) << 16) | ((uint32_t)(v.w & 255) << 24);
      }
    } else {
      const uint4* src = (const uint4*)win;
      uint4* dst = (uint4*)w8;
      const int n16 = wtotal >> 4;
      for (int i = gtid; i < n16; i += nthr) dst[i] = src[i];
    }
    return;
  }

  const bool xf32 = x_is_f32(xin);
  const int row  = blockIdx.x;
  const int lane = tid & 63;
  const int wv   = tid >> 6;
  const size_t base = (size_t)row * (size_t)K;
  __shared__ float wmax[4];

  if (xf32 && K == 4096) {
    const float4* x4 = (const float4*)((const float*)xin + base);
    float4 v[4];
    #pragma unroll
    for (int i = 0; i < 4; ++i) v[i] = x4[i * 256 + tid];
    float mx = 0.0f;
    #pragma unroll
    for (int i = 0; i < 4; ++i)
      mx = fmaxf(mx, fmaxf(fmaxf(fabsf(v[i].x), fabsf(v[i].y)),
                           fmaxf(fabsf(v[i].z), fabsf(v[i].w))));
    #pragma unroll
    for (int off = 32; off; off >>= 1) mx = fmaxf(mx, __shfl_xor(mx, off, 64));
    if (lane == 0) wmax[wv] = mx;
    __syncthreads();
    const float scale =
        fmaxf(fmaxf(wmax[0], wmax[1]), fmaxf(wmax[2], wmax[3])) / 127.0f;
    if (tid == 0) xs[row] = __float2half(scale);
    uint32_t* q = (uint32_t*)(xq + base);
    #pragma unroll
    for (int i = 0; i < 4; ++i) {
      float f[4] = {v[i].x, v[i].y, v[i].z, v[i].w};
      uint32_t p = 0;
      #pragma unroll
      for (int j = 0; j < 4; ++j) {
        float r = fminf(127.0f, fmaxf(-128.0f, rintf(f[j] / scale)));
        p |= ((uint32_t)((int)r & 255)) << (8 * j);
      }
      q[i * 256 + tid] = p;
    }
    return;
  }

  // generic two-pass fallback
  float mx = 0.0f;
  if (xf32) {
    const float* x = (const float*)xin + base;
    for (int k = tid * 4; k < K; k += 256 * 4) {
      float4 v = *(const float4*)(x + k);
      mx = fmaxf(mx, fmaxf(fmaxf(fabsf(v.x), fabsf(v.y)),
                           fmaxf(fabsf(v.z), fabsf(v.w))));
    }
  } else {
    const __half* x = (const __half*)xin + base;
    for (int k = tid * 8; k < K; k += 256 * 8) {
      uint4 u = *(const uint4*)(x + k);
      const __half* hp = (const __half*)&u;
      #pragma unroll
      for (int j = 0; j < 8; ++j) mx = fmaxf(mx, fabsf(__half2float(hp[j])));
    }
  }
  #pragma unroll
  for (int off = 32; off; off >>= 1) mx = fmaxf(mx, __shfl_xor(mx, off, 64));
  if (lane == 0) wmax[wv] = mx;
  __syncthreads();
  const float scale =
      fmaxf(fmaxf(wmax[0], wmax[1]), fmaxf(wmax[2], wmax[3])) / 127.0f;
  if (tid == 0) xs[row] = __float2half(scale);

  for (int k = tid * 8; k < K; k += 256 * 8) {
    float f[8];
    if (xf32) {
      const float* x = (const float*)xin + base;
      float4 a = *(const float4*)(x + k);
      float4 b = *(const float4*)(x + k + 4);
      f[0]=a.x; f[1]=a.y; f[2]=a.z; f[3]=a.w; f[4]=b.x; f[5]=b.y; f[6]=b.z; f[7]=b.w;
    } else {
      const __half* x = (const __half*)xin + base;
      uint4 u = *(const uint4*)(x + k);
      const __half* hp = (const __half*)&u;
      #pragma unroll
      for (int j = 0; j < 8; ++j) f[j] = __half2float(hp[j]);
    }
    uint32_t p0 = 0, p1 = 0;
    #pragma unroll
    for (int j = 0; j < 4; ++j) {
      float r = fminf(127.0f, fmaxf(-128.0f, rintf(f[j] / scale)));
      p0 |= ((uint32_t)((int)r & 255)) << (8 * j);
    }
    #pragma unroll
    for (int j = 0; j < 4; ++j) {
      float r = fminf(127.0f, fmaxf(-128.0f, rintf(f[4 + j] / scale)));
      p1 |= ((uint32_t)((int)r & 255)) << (8 * j);
    }
    uint2 st; st.x = p0; st.y = p1;
    *(uint2*)(xq + base + k) = st;
  }
}

// ---------------------------------------------------------------------------
// int8 GEMM (r12 structure, B-k1 moved off LDS): 256x256 tile, BK=128,
// 8 waves (2Mx4N), mfma_i32_16x16x64_i8. A fully LDS-staged (64KiB dbuf,
// chunk^=(row&7) swizzle); B k0-half LDS-staged (32KiB dbuf, BK64-style
// swizzle); B k1-half read DIRECTLY from global into the SAME 16 VGPRs b1
// occupied in r12 (zero extra registers -- r15's spill trigger avoided).
// LDS port traffic 160->128KB/tile. b1 issued first-in-tile (sched_barrier
// pin) -> counted vmcnt(6) covers it; L2-resident panel, ~800cyc MFMA cover.
// K % 128 == 0, M,N % 256 == 0.
// ---------------------------------------------------------------------------
__global__ __launch_bounds__(512, 2) void gemm_w8a8(
    const int8_t* __restrict__ xq, const int8_t* __restrict__ wq,
    const __half* __restrict__ xs, const float* __restrict__ wscale,
    const float* __restrict__ mos, float* __restrict__ out,
    int M, int N, int K)
{
  __shared__ int8_t sA[2][256 * 128];   // 64 KiB
  __shared__ int8_t sB[2][256 * 64];    // 32 KiB (k0 half only)

  const int tid  = threadIdx.x;
  const int lane = tid & 63;
  const int w    = tid >> 6;
  const int wr   = w >> 2;        // 0..1 -> 128 rows of C
  const int wc   = w & 3;         // 0..3 -> 64 cols of C
  const int lr   = lane & 15;
  const int lk   = lane >> 4;

  // XCD-aware swizzle (bijective: gridDim.x % 8 == 0 for our shapes)
  int L = blockIdx.x;
  const int nwg = gridDim.x;
  if ((nwg & 7) == 0) L = (L & 7) * (nwg >> 3) + (L >> 3);
  const int ntn = N >> 8;
  const int bn = (L % ntn) << 8;
  const int bm = (L / ntn) << 8;

  v4i acc[8][4];
  #pragma unroll
  for (int i = 0; i < 8; ++i)
    #pragma unroll
    for (int j = 0; j < 4; ++j) {
      v4i z = {0, 0, 0, 0};
      acc[i][j] = z;
    }

  // stage A 256x128B tile; LDS slot (r,p) holds global chunk p ^ (r&7)
  auto stageA = [&](int kt, int buf) {
    const int k0 = kt << 7;
    #pragma unroll
    for (int i = 0; i < 4; ++i) {
      const int li = i * 512 + tid;
      const int r  = li >> 3;
      const int p  = li & 7;
      const int sc = p ^ (r & 7);
      GLOAD_LDS16(xq + (size_t)(bm + r) * K + k0 + (sc << 4),
                  &sA[buf][(i * 512 + (w << 6)) << 4]);
    }
  };
  // stage B k0-half: 256 rows x 64B; slot (r,p) holds chunk p ^ ((r>>1)&3)
  auto stageB = [&](int kt, int buf) {
    const int k0 = kt << 7;
    #pragma unroll
    for (int i = 0; i < 2; ++i) {
      const int li = i * 512 + tid;
      const int r  = li >> 2;
      const int p  = li & 3;
      const int sc = p ^ ((r >> 1) & 3);
      GLOAD_LDS16(wq + (size_t)(bn + r) * K + k0 + (sc << 4),
                  &sB[buf][(i * 512 + (w << 6)) << 4]);
    }
  };

  // swizzled ds_read byte offsets. A: row&7 == lr&7 (row bases are x16).
  const int rowA0 = (wr << 7) + lr;
  const int aoff0 = rowA0 * 128 + ((lk ^ (lr & 7)) << 4);
  const int aoff1 = aoff0 ^ 64;
  // B k0: 64B rows, slot = lk ^ ((row>>1)&3); invariant under row += 16
  const int rowB0 = (wc << 6) + lr;
  const int boff0 = rowB0 * 64 + ((lk ^ ((rowB0 >> 1) & 3)) << 4);

  // B k1-half global pointer: row = bn + wc*64 + lr (+ni*16), byte lk*16+64
  const int8_t* wrow1 = wq + (size_t)(bn + (wc << 6) + lr) * K + (lk << 4) + 64;
  const size_t nstep = (size_t)16 * (size_t)K;

  const int nt = K >> 7;   // 32 for K=4096

  // prologue
  stageA(0, 0); stageB(0, 0);
  asm volatile("s_waitcnt vmcnt(0)" ::: "memory");
  __builtin_amdgcn_s_barrier();

  #pragma unroll 1
  for (int t = 0; t < nt; ++t) {
    const int buf = t & 1;
    const int8_t* Ab = sA[buf];
    const int8_t* Bb = sB[buf];
    const bool do_stage = (t + 1 < nt);
    v4i a00[4], a10[4], a01[4], a11[4], b0[4], b1[4];

    // b1 (B k1-half) direct from global -- MUST be the oldest vm ops of
    // this tile for the vmcnt(6) below; sched_barrier pins issue order.
    #pragma unroll
    for (int ni = 0; ni < 4; ++ni)
      b1[ni] = *(const v4i*)(wrow1 + ni * nstep + ((size_t)t << 7));
    __builtin_amdgcn_sched_barrier(0);

    // gate burst: kk=0 h0 A-frags + kk=0 B-frags (8 LDS reads)
    #pragma unroll
    for (int j = 0; j < 4; ++j) a00[j] = *(const v4i*)(Ab + aoff0 + j * 2048);
    #pragma unroll
    for (int j = 0; j < 4; ++j) b0[j]  = *(const v4i*)(Bb + boff0 + j * 1024);

    if (do_stage) stageA(t + 1, buf ^ 1);        // 4 gloads

    asm volatile("s_waitcnt lgkmcnt(0)" ::: "memory");
    __builtin_amdgcn_s_setprio(1);
    #pragma unroll
    for (int j = 0; j < 4; ++j)
      #pragma unroll
      for (int ni = 0; ni < 4; ++ni)
        acc[j][ni] = __builtin_amdgcn_mfma_i32_16x16x64_i8(
            a00[j], b0[ni], acc[j][ni], 0, 0, 0);
    __builtin_amdgcn_s_setprio(0);

    // under-cover burst: h1/k0 A, h0/k1 A (8 reads)
    #pragma unroll
    for (int j = 0; j < 4; ++j) a10[j] = *(const v4i*)(Ab + aoff0 + 8192 + j * 2048);
    #pragma unroll
    for (int j = 0; j < 4; ++j) a01[j] = *(const v4i*)(Ab + aoff1 + j * 2048);

    if (do_stage) stageB(t + 1, buf ^ 1);        // 2 gloads

    asm volatile("s_waitcnt lgkmcnt(4)" ::: "memory");   // a10 landed
    __builtin_amdgcn_s_setprio(1);
    #pragma unroll
    for (int j = 0; j < 4; ++j)
      #pragma unroll
      for (int ni = 0; ni < 4; ++ni)
        acc[4 + j][ni] = __builtin_amdgcn_mfma_i32_16x16x64_i8(
            a10[j], b0[ni], acc[4 + j][ni], 0, 0, 0);
    __builtin_amdgcn_s_setprio(0);

    // last A burst (4 reads)
    #pragma unroll
    for (int j = 0; j < 4; ++j) a11[j] = *(const v4i*)(Ab + aoff1 + 8192 + j * 2048);

    // b1 must have landed: oldest 4 of (b1:4, stageA:4, stageB:2)
    if (do_stage) {
      asm volatile("s_waitcnt vmcnt(6)" ::: "memory");
    } else {
      asm volatile("s_waitcnt vmcnt(0)" ::: "memory");
    }
    asm volatile("s_waitcnt lgkmcnt(4)" ::: "memory");   // a01 landed
    __builtin_amdgcn_s_setprio(1);
    #pragma unroll
    for (int j = 0; j < 4; ++j)
      #pragma unroll
      for (int ni = 0; ni < 4; ++ni)
        acc[j][ni] = __builtin_amdgcn_mfma_i32_16x16x64_i8(
            a01[j], b1[ni], acc[j][ni], 0, 0, 0);
    __builtin_amdgcn_s_setprio(0);

    asm volatile("s_waitcnt lgkmcnt(0)" ::: "memory");   // a11 landed
    __builtin_amdgcn_s_setprio(1);
    #pragma unroll
    for (int j = 0; j < 4; ++j)
      #pragma unroll
      for (int ni = 0; ni < 4; ++ni)
        acc[4 + j][ni] = __builtin_amdgcn_mfma_i32_16x16x64_i8(
            a11[j], b1[ni], acc[4 + j][ni], 0, 0, 0);
    __builtin_amdgcn_s_setprio(0);

    // stage(t+1) must be fully resident before next iter's reads
    asm volatile("s_waitcnt vmcnt(0)" ::: "memory");
    __builtin_amdgcn_s_barrier();
  }

  // epilogue: out = (float(half(acc*s_out)) * wscale[n]) * float(half_scale[m])
  const float s_out = mos[0];
  #pragma unroll
  for (int ni = 0; ni < 4; ++ni) {
    const int n_g = bn + (wc << 6) + ni * 16 + lr;
    const float wsc = wscale[n_g];
    #pragma unroll
    for (int mi = 0; mi < 8; ++mi) {
      #pragma unroll
      for (int j = 0; j < 4; ++j) {
        const int m_g = bm + (wr << 7) + mi * 16 + lk * 4 + j;
        const float y = __half2float(__float2half((float)acc[mi][ni][j] * s_out));
        out[(size_t)m_g * N + n_g] = (y * wsc) * __half2float(xs[m_g]);
      }
    }
  }
}

// ---------------------------------------------------------------------------
extern "C" void kernel_launch(void* const* d_in, const int* in_sizes, int n_in,
                              void* d_out, int out_size, void* d_ws, size_t ws_size,
                              hipStream_t stream) {
  const void*  x      = d_in[0];
  const void*  win    = d_in[1];
  const float* wscale = (const float*)d_in[2];
  const float* mos    = (const float*)d_in[3];
  float*       out    = (float*)d_out;

  const int N = in_sizes[2];            // 4096
  const int K = in_sizes[1] / N;        // 4096
  const int M = in_sizes[0] / K;        // 8192 (B*S)

  int8_t* xq = (int8_t*)d_ws + XQ_OFF;
  __half* xs = (__half*)((char*)d_ws + XS_OFF);
  int8_t* w8 = (int8_t*)d_ws + W8_OFF;

  prologue<<<M + RW_BLOCKS, 256, 0, stream>>>(x, win, xq, xs, w8, K, M, N * K);

  gemm_w8a8<<<dim3((M >> 8) * (N >> 8)), 512, 0, stream>>>(
      xq, w8, xs, wscale, mos, out, M, N, K);
}

// Round 18
// 203.489 us; speedup vs baseline: 1.0699x; 1.0699x over previous
//
#include <hip/hip_runtime.h>
#include <hip/hip_fp16.h>
#include <stdint.h>

typedef int v4i __attribute__((ext_vector_type(4)));

#define GLOAD_LDS16(g, l) __builtin_amdgcn_global_load_lds(                  \
    (const __attribute__((address_space(1))) void*)(g),                      \
    (__attribute__((address_space(3))) void*)(l), 16, 0, 0)

// workspace layout (bytes)
#define XQ_OFF 0u
#define XS_OFF 33554432u              // M*K int8
#define W8_OFF 33570816u              // + M*2 fp16 scales

// ---------------------------------------------------------------------------
// Self-classification of input delivery: x widened fp16->f32 has low 13
// mantissa bits zero; w widened int8->int32 has every word in [-128,127].
// ---------------------------------------------------------------------------
__device__ inline bool x_is_f32(const void* xin) {
  const uint32_t* xw = (const uint32_t*)xin;
  bool ok = true;
  #pragma unroll
  for (int i = 0; i < 16; ++i) ok &= ((xw[i] & 0x1FFFu) == 0u);
  return ok;
}
__device__ inline bool w_is_i32(const void* win) {
  const int* wi = (const int*)win;
  bool ok = true;
  #pragma unroll
  for (int i = 0; i < 16; ++i) ok &= (wi[i] >= -128 && wi[i] <= 127);
  return ok;
}

// ---------------------------------------------------------------------------
// Fused prologue: blocks [0, M) quant x rows; blocks [M, M+RW_BLOCKS) repack w.
// ---------------------------------------------------------------------------
#define RW_BLOCKS 1024

__global__ __launch_bounds__(256) void prologue(
    const void* __restrict__ xin, const void* __restrict__ win,
    int8_t* __restrict__ xq, __half* __restrict__ xs,
    int8_t* __restrict__ w8, int K, int M, int wtotal)
{
  const int tid = threadIdx.x;

  if (blockIdx.x >= (unsigned)M) {
    const bool as32 = w_is_i32(win);
    const int bid  = blockIdx.x - M;
    const int gtid = bid * 256 + tid;
    const int nthr = RW_BLOCKS * 256;
    if (as32) {
      const int4* w4 = (const int4*)win;
      uint32_t* dst = (uint32_t*)w8;
      const int n4 = wtotal >> 2;
      for (int i = gtid; i < n4; i += nthr) {
        int4 v = w4[i];
        dst[i] = (uint32_t)(v.x & 255) | ((uint32_t)(v.y & 255) << 8) |
                 ((uint32_t)(v.z & 255) << 16) | ((uint32_t)(v.w & 255) << 24);
      }
    } else {
      const uint4* src = (const uint4*)win;
      uint4* dst = (uint4*)w8;
      const int n16 = wtotal >> 4;
      for (int i = gtid; i < n16; i += nthr) dst[i] = src[i];
    }
    return;
  }

  const bool xf32 = x_is_f32(xin);
  const int row  = blockIdx.x;
  const int lane = tid & 63;
  const int wv   = tid >> 6;
  const size_t base = (size_t)row * (size_t)K;
  __shared__ float wmax[4];

  if (xf32 && K == 4096) {
    const float4* x4 = (const float4*)((const float*)xin + base);
    float4 v[4];
    #pragma unroll
    for (int i = 0; i < 4; ++i) v[i] = x4[i * 256 + tid];
    float mx = 0.0f;
    #pragma unroll
    for (int i = 0; i < 4; ++i)
      mx = fmaxf(mx, fmaxf(fmaxf(fabsf(v[i].x), fabsf(v[i].y)),
                           fmaxf(fabsf(v[i].z), fabsf(v[i].w))));
    #pragma unroll
    for (int off = 32; off; off >>= 1) mx = fmaxf(mx, __shfl_xor(mx, off, 64));
    if (lane == 0) wmax[wv] = mx;
    __syncthreads();
    const float scale =
        fmaxf(fmaxf(wmax[0], wmax[1]), fmaxf(wmax[2], wmax[3])) / 127.0f;
    if (tid == 0) xs[row] = __float2half(scale);
    uint32_t* q = (uint32_t*)(xq + base);
    #pragma unroll
    for (int i = 0; i < 4; ++i) {
      float f[4] = {v[i].x, v[i].y, v[i].z, v[i].w};
      uint32_t p = 0;
      #pragma unroll
      for (int j = 0; j < 4; ++j) {
        float r = fminf(127.0f, fmaxf(-128.0f, rintf(f[j] / scale)));
        p |= ((uint32_t)((int)r & 255)) << (8 * j);
      }
      q[i * 256 + tid] = p;
    }
    return;
  }

  // generic two-pass fallback
  float mx = 0.0f;
  if (xf32) {
    const float* x = (const float*)xin + base;
    for (int k = tid * 4; k < K; k += 256 * 4) {
      float4 v = *(const float4*)(x + k);
      mx = fmaxf(mx, fmaxf(fmaxf(fabsf(v.x), fabsf(v.y)),
                           fmaxf(fabsf(v.z), fabsf(v.w))));
    }
  } else {
    const __half* x = (const __half*)xin + base;
    for (int k = tid * 8; k < K; k += 256 * 8) {
      uint4 u = *(const uint4*)(x + k);
      const __half* hp = (const __half*)&u;
      #pragma unroll
      for (int j = 0; j < 8; ++j) mx = fmaxf(mx, fabsf(__half2float(hp[j])));
    }
  }
  #pragma unroll
  for (int off = 32; off; off >>= 1) mx = fmaxf(mx, __shfl_xor(mx, off, 64));
  if (lane == 0) wmax[wv] = mx;
  __syncthreads();
  const float scale =
      fmaxf(fmaxf(wmax[0], wmax[1]), fmaxf(wmax[2], wmax[3])) / 127.0f;
  if (tid == 0) xs[row] = __float2half(scale);

  for (int k = tid * 8; k < K; k += 256 * 8) {
    float f[8];
    if (xf32) {
      const float* x = (const float*)xin + base;
      float4 a = *(const float4*)(x + k);
      float4 b = *(const float4*)(x + k + 4);
      f[0]=a.x; f[1]=a.y; f[2]=a.z; f[3]=a.w; f[4]=b.x; f[5]=b.y; f[6]=b.z; f[7]=b.w;
    } else {
      const __half* x = (const __half*)xin + base;
      uint4 u = *(const uint4*)(x + k);
      const __half* hp = (const __half*)&u;
      #pragma unroll
      for (int j = 0; j < 8; ++j) f[j] = __half2float(hp[j]);
    }
    uint32_t p0 = 0, p1 = 0;
    #pragma unroll
    for (int j = 0; j < 4; ++j) {
      float r = fminf(127.0f, fmaxf(-128.0f, rintf(f[j] / scale)));
      p0 |= ((uint32_t)((int)r & 255)) << (8 * j);
    }
    #pragma unroll
    for (int j = 0; j < 4; ++j) {
      float r = fminf(127.0f, fmaxf(-128.0f, rintf(f[4 + j] / scale)));
      p1 |= ((uint32_t)((int)r & 255)) << (8 * j);
    }
    uint2 st; st.x = p0; st.y = p1;
    *(uint2*)(xq + base + k) = st;
  }
}

// ---------------------------------------------------------------------------
// int8 GEMM, m201-faithful 4-phase schedule: 256x256 tile, BK=64, 8 waves
// (2Mx4N), quad-buffered LDS ring (128KiB). Iteration = 2 K-tiles = 4 phases;
// each phase = {ds_read subtile (4-8 b128) | trickle-stage 2 gloads | BAR |
// lgkm(0) | setprio 16xMFMA | [odd phases: vmcnt(4)] BAR}. vmcnt(4) is
// minimal-counted: leaves exactly the 2 newest stage-pairs outstanding,
// guarantees the tile read in the NEXT phase is LDS-resident. vmcnt(0) only
// in the final iteration. Swizzle g(r)=(r>>1)&3 (verified 0-conflict).
// Requires K % 128 == 0, K/64 >= 4, M,N % 256 == 0.
// ---------------------------------------------------------------------------
__global__ __launch_bounds__(512, 2) void gemm_w8a8(
    const int8_t* __restrict__ xq, const int8_t* __restrict__ wq,
    const __half* __restrict__ xs, const float* __restrict__ wscale,
    const float* __restrict__ mos, float* __restrict__ out,
    int M, int N, int K)
{
  __shared__ int8_t sA[4][256 * 64];   // 64 KiB
  __shared__ int8_t sB[4][256 * 64];   // 64 KiB

  const int tid  = threadIdx.x;
  const int lane = tid & 63;
  const int w    = tid >> 6;
  const int wr   = w >> 2;        // 0..1 -> 128 rows of C
  const int wc   = w & 3;         // 0..3 -> 64 cols of C
  const int lr   = lane & 15;
  const int lk   = lane >> 4;

  // XCD-aware swizzle (bijective: gridDim.x % 8 == 0 for our shapes)
  int L = blockIdx.x;
  const int nwg = gridDim.x;
  if ((nwg & 7) == 0) L = (L & 7) * (nwg >> 3) + (L >> 3);
  const int ntn = N >> 8;
  const int bn = (L % ntn) << 8;
  const int bm = (L / ntn) << 8;

  v4i acc[8][4];
  #pragma unroll
  for (int i = 0; i < 8; ++i)
    #pragma unroll
    for (int j = 0; j < 4; ++j) {
      v4i z = {0, 0, 0, 0};
      acc[i][j] = z;
    }

  // stage 256x64B tile (2 loads/thread); LDS (r,p) holds chunk p ^ ((r>>1)&3)
  auto stageA = [&](int kt, int buf) {
    const int k0 = kt << 6;
    #pragma unroll
    for (int i = 0; i < 2; ++i) {
      const int li = i * 512 + tid;
      const int r  = li >> 2;
      const int p  = li & 3;
      const int sc = p ^ ((r >> 1) & 3);
      GLOAD_LDS16(xq + (size_t)(bm + r) * K + k0 + (sc << 4),
                  &sA[buf][(i * 512 + (w << 6)) << 4]);
    }
  };
  auto stageB = [&](int kt, int buf) {
    const int k0 = kt << 6;
    #pragma unroll
    for (int i = 0; i < 2; ++i) {
      const int li = i * 512 + tid;
      const int r  = li >> 2;
      const int p  = li & 3;
      const int sc = p ^ ((r >> 1) & 3);
      GLOAD_LDS16(wq + (size_t)(bn + r) * K + k0 + (sc << 4),
                  &sB[buf][(i * 512 + (w << 6)) << 4]);
    }
  };

  // swizzled ds_read byte offsets; invariant under row += 16 steps
  const int rowA0 = (wr << 7) + lr;
  const int aoff  = rowA0 * 64 + ((lk ^ ((rowA0 >> 1) & 3)) << 4);
  const int rowB0 = (wc << 6) + lr;
  const int boff  = rowB0 * 64 + ((lk ^ ((rowB0 >> 1) & 3)) << 4);

  const int nt = K >> 6;   // 64 for K=4096 (even, >= 4)

#define MFMA16(BASE, AV, BV)                                                 \
    __builtin_amdgcn_s_setprio(1);                                           \
    _Pragma("unroll")                                                        \
    for (int mi = 0; mi < 4; ++mi)                                           \
      _Pragma("unroll")                                                      \
      for (int ni = 0; ni < 4; ++ni)                                         \
        acc[(BASE) + mi][ni] = __builtin_amdgcn_mfma_i32_16x16x64_i8(        \
            AV[mi], BV[ni], acc[(BASE) + mi][ni], 0, 0, 0);                  \
    __builtin_amdgcn_s_setprio(0);

  // prologue: stage tiles 0,1; guarantee tile 0 resident (tile 1 stays out)
  stageA(0, 0); stageB(0, 0);
  stageA(1, 1); stageB(1, 1);
  asm volatile("s_waitcnt vmcnt(4)" ::: "memory");
  __builtin_amdgcn_s_barrier();

  #pragma unroll 1
  for (int t = 0; t < nt; t += 2) {
    const bool ds2 = (t + 2 < nt);
    const bool ds3 = (t + 3 < nt);
    const int8_t* A0 = sA[t & 3];
    const int8_t* B0 = sB[t & 3];
    const int8_t* A1 = sA[(t + 1) & 3];
    const int8_t* B1 = sB[(t + 1) & 3];
    v4i a[4], bf0[4], bf1[4];

    // ---- P0: tile t, acc[0..3] (tile t resident per prev P3's vmcnt+BAR)
    #pragma unroll
    for (int j = 0; j < 4; ++j) bf0[j] = *(const v4i*)(B0 + boff + j * 1024);
    #pragma unroll
    for (int j = 0; j < 4; ++j) a[j]   = *(const v4i*)(A0 + aoff + j * 1024);
    if (ds2) stageA(t + 2, (t + 2) & 3);
    __builtin_amdgcn_s_barrier();
    asm volatile("s_waitcnt lgkmcnt(0)" ::: "memory");
    MFMA16(0, a, bf0)
    __builtin_amdgcn_s_barrier();

    // ---- P1: tile t, acc[4..7]
    #pragma unroll
    for (int j = 0; j < 4; ++j) a[j] = *(const v4i*)(A0 + aoff + 4096 + j * 1024);
    if (ds2) stageB(t + 2, (t + 2) & 3);
    __builtin_amdgcn_s_barrier();
    asm volatile("s_waitcnt lgkmcnt(0)" ::: "memory");
    MFMA16(4, a, bf0)
    // guarantee tile t+1 resident for P2 reads (leaves A/B(t+2) outstanding)
    if (ds2) { asm volatile("s_waitcnt vmcnt(4)" ::: "memory"); }
    else     { asm volatile("s_waitcnt vmcnt(0)" ::: "memory"); }
    __builtin_amdgcn_s_barrier();

    // ---- P2: tile t+1, acc[0..3]
    #pragma unroll
    for (int j = 0; j < 4; ++j) bf1[j] = *(const v4i*)(B1 + boff + j * 1024);
    #pragma unroll
    for (int j = 0; j < 4; ++j) a[j]   = *(const v4i*)(A1 + aoff + j * 1024);
    if (ds3) stageA(t + 3, (t + 3) & 3);
    __builtin_amdgcn_s_barrier();
    asm volatile("s_waitcnt lgkmcnt(0)" ::: "memory");
    MFMA16(0, a, bf1)
    __builtin_amdgcn_s_barrier();

    // ---- P3: tile t+1, acc[4..7]
    #pragma unroll
    for (int j = 0; j < 4; ++j) a[j] = *(const v4i*)(A1 + aoff + 4096 + j * 1024);
    if (ds3) stageB(t + 3, (t + 3) & 3);
    __builtin_amdgcn_s_barrier();
    asm volatile("s_waitcnt lgkmcnt(0)" ::: "memory");
    MFMA16(4, a, bf1)
    // guarantee tile t+2 resident for next P0 (leaves A/B(t+3) outstanding)
    if (ds3) { asm volatile("s_waitcnt vmcnt(4)" ::: "memory"); }
    else     { asm volatile("s_waitcnt vmcnt(0)" ::: "memory"); }
    __builtin_amdgcn_s_barrier();
  }
#undef MFMA16

  // epilogue: out = (float(half(acc*s_out)) * wscale[n]) * float(half_scale[m])
  const float s_out = mos[0];
  #pragma unroll
  for (int ni = 0; ni < 4; ++ni) {
    const int n_g = bn + (wc << 6) + ni * 16 + lr;
    const float wsc = wscale[n_g];
    #pragma unroll
    for (int mi = 0; mi < 8; ++mi) {
      #pragma unroll
      for (int j = 0; j < 4; ++j) {
        const int m_g = bm + (wr << 7) + mi * 16 + lk * 4 + j;
        const float y = __half2float(__float2half((float)acc[mi][ni][j] * s_out));
        out[(size_t)m_g * N + n_g] = (y * wsc) * __half2float(xs[m_g]);
      }
    }
  }
}

// ---------------------------------------------------------------------------
extern "C" void kernel_launch(void* const* d_in, const int* in_sizes, int n_in,
                              void* d_out, int out_size, void* d_ws, size_t ws_size,
                              hipStream_t stream) {
  const void*  x      = d_in[0];
  const void*  win    = d_in[1];
  const float* wscale = (const float*)d_in[2];
  const float* mos    = (const float*)d_in[3];
  float*       out    = (float*)d_out;

  const int N = in_sizes[2];            // 4096
  const int K = in_sizes[1] / N;        // 4096
  const int M = in_sizes[0] / K;        // 8192 (B*S)

  int8_t* xq = (int8_t*)d_ws + XQ_OFF;
  __half* xs = (__half*)((char*)d_ws + XS_OFF);
  int8_t* w8 = (int8_t*)d_ws + W8_OFF;

  prologue<<<M + RW_BLOCKS, 256, 0, stream>>>(x, win, xq, xs, w8, K, M, N * K);

  gemm_w8a8<<<dim3((M >> 8) * (N >> 8)), 512, 0, stream>>>(
      xq, w8, xs, wscale, mos, out, M, N, K);
}